// Round 14
// baseline (153.457 us; speedup 1.0000x reference)
//
#include <hip/hip_runtime.h>
#include <stdint.h>
#include <stddef.h>

// Match numpy float32 rounding: forbid fma contraction in all float math below.
#pragma clang fp contract(off)

#define N8   819200u
#define N16  204800u
#define N32  51200u
#define NTOT 1075200u
#define TOPK 2048
#define CAND_MAX 8192
#define NBIN 8192u
#define BINSHIFT 10
#define NMS_THR 0.4f
#define DET_THR 0.5f

// ws byte offsets
#define OFF_HIST   0u        // u32[8192]    32KB
#define OFF_META   32768u    // u32[16]
#define OFF_CAND   32832u    // u64[8192]    64KB
#define OFF_TIDX   98368u    // u32[2048]
#define OFF_TCONF  106560u   // f32[2048]
#define OFF_BOX    114752u   // f32[2048*4]  (16B aligned)
#define OFF_DIAGT  147520u   // u32[32][64]  8KB, [rowk][chunk]
#define OFF_SUPPT  155968u   // u32[64][32][64] = 512KB, [chunk][row][word]

__device__ __forceinline__ float load_conf(unsigned a, const float* __restrict__ s8,
                                           const float* __restrict__ s16,
                                           const float* __restrict__ s32) {
  if (a < N8) return s8[a];
  if (a < N8 + N16) return s16[a - N8];
  return s32[a - (N8 + N16)];
}

__device__ __forceinline__ void decode(unsigned a,
    const float* __restrict__ b8, const float* __restrict__ l8,
    const float* __restrict__ b16, const float* __restrict__ l16,
    const float* __restrict__ b32, const float* __restrict__ l32,
    float& cx, float& cy, float& s, const float*& bb, const float*& lm) {
  if (a < N8) {
    unsigned cell = a >> 1;
    cx = (float)((cell % 640u) * 8u); cy = (float)((cell / 640u) * 8u);
    s = 8.f; bb = b8 + (size_t)a * 4; lm = l8 + (size_t)a * 10;
  } else if (a < N8 + N16) {
    unsigned loc = a - N8; unsigned cell = loc >> 1;
    cx = (float)((cell % 320u) * 16u); cy = (float)((cell / 320u) * 16u);
    s = 16.f; bb = b16 + (size_t)loc * 4; lm = l16 + (size_t)loc * 10;
  } else {
    unsigned loc = a - (N8 + N16); unsigned cell = loc >> 1;
    cx = (float)((cell % 160u) * 32u); cy = (float)((cell / 160u) * 32u);
    s = 32.f; bb = b32 + (size_t)loc * 4; lm = l32 + (size_t)loc * 10;
  }
}

// K1: histogram of conf>=0.5 on 13-bit prefix of (bits - bits(0.5))
__global__ void k_hist(const float* __restrict__ s8, const float* __restrict__ s16,
                       const float* __restrict__ s32, unsigned* __restrict__ hist) {
  unsigned i = blockIdx.x * blockDim.x + threadIdx.x;
  unsigned st = gridDim.x * blockDim.x;
  for (unsigned a = i; a < NTOT; a += st) {
    float c = load_conf(a, s8, s16, s32);
    if (c >= DET_THR) {
      unsigned v = (__float_as_uint(c) - 0x3F000000u) >> BINSHIFT;
      if (v > NBIN - 1u) v = NBIN - 1u;
      atomicAdd(&hist[v], 1u);
    }
  }
}

// K2: find cutoff prefix (smallest p with suffix-count >= TOPK); single WG
__global__ void __launch_bounds__(1024) k_scan(const unsigned* __restrict__ hist,
                                               unsigned* __restrict__ meta) {
  __shared__ unsigned suf[1024];
  int t = threadIdx.x;
  const unsigned* hp = hist + (size_t)t * 8;
  unsigned s = 0;
  for (int b = 0; b < 8; b++) s += hp[b];
  suf[t] = s;
  __syncthreads();
  for (int d = 1; d < 1024; d <<= 1) {
    unsigned v = (t + d < 1024) ? suf[t + d] : 0u;
    __syncthreads();
    suf[t] += v;
    __syncthreads();
  }
  unsigned total = suf[0];
  unsigned mine = suf[t];
  unsigned nxt = (t < 1023) ? suf[t + 1] : 0u;
  if (total < (unsigned)TOPK) {
    if (t == 0) { meta[0] = 0u; meta[2] = total; }
    return;
  }
  if (mine >= (unsigned)TOPK && nxt < (unsigned)TOPK) {
    unsigned run = nxt, cut = (unsigned)t * 8u;
    for (int b = 7; b >= 0; b--) {
      run += hp[b];
      if (run >= (unsigned)TOPK) { cut = (unsigned)t * 8u + (unsigned)b; break; }
    }
    meta[0] = cut; meta[2] = total;
  }
}

// K3: compact candidates (>= cutoff prefix) as 64-bit sort keys
__global__ void k_compact(const float* __restrict__ s8, const float* __restrict__ s16,
                          const float* __restrict__ s32, unsigned* __restrict__ meta,
                          unsigned long long* __restrict__ cand) {
  unsigned cut = meta[0];
  unsigned i = blockIdx.x * blockDim.x + threadIdx.x;
  unsigned st = gridDim.x * blockDim.x;
  for (unsigned a = i; a < NTOT; a += st) {
    float c = load_conf(a, s8, s16, s32);
    if (c >= DET_THR) {
      unsigned b = __float_as_uint(c);
      unsigned v = (b - 0x3F000000u) >> BINSHIFT;
      if (v >= cut) {
        unsigned pos = atomicAdd(&meta[3], 1u);
        if (pos < (unsigned)CAND_MAX)
          cand[pos] = ((unsigned long long)b << 32) |
                      (unsigned long long)(0xFFFFFFFFu - a);
      }
    }
  }
}

// K4: rank-and-scatter. Keys unique -> rank(x)=#{y>x} is a permutation.
__global__ void __launch_bounds__(256) k_rank(
    const unsigned long long* __restrict__ cand, const unsigned* __restrict__ meta,
    const float* __restrict__ b8, const float* __restrict__ l8,
    const float* __restrict__ b16, const float* __restrict__ l16,
    const float* __restrict__ b32, const float* __restrict__ l32,
    const float* __restrict__ dsp,
    unsigned* __restrict__ tidx, float* __restrict__ tconf, float* __restrict__ box) {
  unsigned count = meta[3];
  if (count > (unsigned)CAND_MAX) count = (unsigned)CAND_MAX;
  unsigned wave = blockIdx.x * 4u + (threadIdx.x >> 6);
  unsigned lane = threadIdx.x & 63u;
  if (wave >= count) return;
  unsigned long long my = cand[wave];
  unsigned cnt = 0;
  for (unsigned i = lane; i < count; i += 64u)
    cnt += (cand[i] > my) ? 1u : 0u;
  for (int d = 32; d > 0; d >>= 1) cnt += __shfl_down(cnt, d);
  if (lane == 0 && cnt < (unsigned)TOPK) {
    unsigned r = cnt;
    unsigned a = 0xFFFFFFFFu - (unsigned)(my & 0xFFFFFFFFull);
    float conf = __uint_as_float((unsigned)(my >> 32));
    float cx, cy, s; const float* bb; const float* lm;
    decode(a, b8, l8, b16, l16, b32, l32, cx, cy, s, bb, lm);
    float ds = dsp[0];
    float b0 = bb[0] * s, b1 = bb[1] * s, b2 = bb[2] * s, b3 = bb[3] * s;
    box[r * 4 + 0] = (cx - b0) / ds;
    box[r * 4 + 1] = (cy - b1) / ds;
    box[r * 4 + 2] = (cx + b2) / ds;
    box[r * 4 + 3] = (cy + b3) / ds;
    tidx[r] = a; tconf[r] = conf;
  }
}

// K5: suppression matrix: supp[chunk i>>5][row i&31][word64], bit[i][j] =
// (iou > thr) && (j > i). diagT[i&31][i>>5] = chunk-diagonal u32 word.
// Nontemporal stores keep lines out of the 8 writer-XCD L2s.
__global__ void __launch_bounds__(256) k_supp(const float* __restrict__ box,
                                              unsigned long long* __restrict__ supp64,
                                              unsigned* __restrict__ diagT) {
  int i = blockIdx.x;
  const float4 bi = ((const float4*)box)[i];
  float ai = fmaxf(bi.z - bi.x, 0.f) * fmaxf(bi.w - bi.y, 0.f);
  int tid = threadIdx.x;
  int lane = tid & 63, wv = tid >> 6;
  int c = i >> 5, k = i & 31;
  for (int base = 0; base < TOPK; base += 256) {
    int j = base + tid;
    const float4 bj = ((const float4*)box)[j];
    float aj = fmaxf(bj.z - bj.x, 0.f) * fmaxf(bj.w - bj.y, 0.f);
    float ltx = fmaxf(bi.x, bj.x), lty = fmaxf(bi.y, bj.y);
    float rbx = fminf(bi.z, bj.z), rby = fminf(bi.w, bj.w);
    float w = fmaxf(rbx - ltx, 0.f), h = fmaxf(rby - lty, 0.f);
    float inter = w * h;
    float iou = inter / (ai + aj - inter + 1e-9f);
    bool pred = (iou > NMS_THR) && (j > i);
    unsigned long long word = __ballot(pred);
    int w64 = (base >> 6) + wv;
    if (lane == 0) {
      __builtin_nontemporal_store(word, &supp64[(size_t)c * 1024 + k * 32 + w64]);
      if (w64 == (i >> 6))
        __builtin_nontemporal_store(
            (unsigned)(word >> (((i >> 5) & 1) * 32)), &diagT[k * 64 + c]);
    }
  }
}

// K6: word-partitioned 8-wave greedy NMS + output (512 threads).
// Wave v owns column words [8v,8v+8): its accumulated suppression lives in
// registers A0..A3 (even lanes: words 8v+0..3, odd lanes: 8v+4..7) and is
// updated by applying EVERY kept chunk to only its words (5-step
// parity-preserving shfl_xor OR-reduce; even/odd lanes each cover all 32
// rows once). Chunk c's serial closure runs on its owner wave (c>>3), which
// holds word c in registers: readlane(A)+dg SALU chain, then lane 0
// publishes keepw[c] + release flag in LDS; waves v>g acquire-poll.
// No barriers in the loop; loads are 1 dwordx4/lane/chunk, 8-deep rotation,
// independent of keep state (streams at 8-wave MLP).
__global__ void __launch_bounds__(512, 1) k_nms_out(
    const unsigned* __restrict__ supp_t, const unsigned* __restrict__ diagT,
    const unsigned* __restrict__ meta,
    const unsigned* __restrict__ tidx, const float* __restrict__ tconf,
    const float* __restrict__ b8, const float* __restrict__ l8,
    const float* __restrict__ b16, const float* __restrict__ l16,
    const float* __restrict__ b32, const float* __restrict__ l32,
    const float* __restrict__ dsp, float* __restrict__ out) {
  __shared__ unsigned keepw[64];
  __shared__ unsigned flagw[64];
  const int tid = threadIdx.x;
  const int v = tid >> 6, l = tid & 63;
  const int par = l & 1, row_ = l >> 1;
  unsigned count = meta[3];
  if (count > (unsigned)TOPK) count = (unsigned)TOPK;
  if (tid < 64) { keepw[tid] = 0u; flagw[tid] = 0u; }
  // diag preload (every wave, redundant): dg[k] lane c = diag of row 32c+k
  unsigned dg[32];
#pragma unroll
  for (int k = 0; k < 32; k++) dg[k] = diagT[k * 64 + l];
  // lane's slice: words [8v+par*4, +4) of row row_, per chunk (16B dwordx4)
  const uint4* bp = (const uint4*)supp_t + ((size_t)(row_ * 16 + v * 2 + par));
  __syncthreads();
  uint4 P0 = bp[0 * 512], P1 = bp[1 * 512], P2 = bp[2 * 512], P3 = bp[3 * 512];
  uint4 P4 = bp[4 * 512], P5 = bp[5 * 512], P6 = bp[6 * 512], P7 = bp[7 * 512];
  unsigned A0 = 0u, A1 = 0u, A2 = 0u, A3 = 0u;

#define NMS_APPLY(WS, PB)                                                     \
  {                                                                           \
    unsigned m_ = (unsigned)((int)((WS) << (31 - row_)) >> 31);               \
    unsigned x0 = PB.x & m_, x1 = PB.y & m_, x2 = PB.z & m_, x3 = PB.w & m_;  \
    x0 |= __shfl_xor(x0, 2);  x1 |= __shfl_xor(x1, 2);                        \
    x2 |= __shfl_xor(x2, 2);  x3 |= __shfl_xor(x3, 2);                        \
    x0 |= __shfl_xor(x0, 4);  x1 |= __shfl_xor(x1, 4);                        \
    x2 |= __shfl_xor(x2, 4);  x3 |= __shfl_xor(x3, 4);                        \
    x0 |= __shfl_xor(x0, 8);  x1 |= __shfl_xor(x1, 8);                        \
    x2 |= __shfl_xor(x2, 8);  x3 |= __shfl_xor(x3, 8);                        \
    x0 |= __shfl_xor(x0, 16); x1 |= __shfl_xor(x1, 16);                       \
    x2 |= __shfl_xor(x2, 16); x3 |= __shfl_xor(x3, 16);                       \
    x0 |= __shfl_xor(x0, 32); x1 |= __shfl_xor(x1, 32);                       \
    x2 |= __shfl_xor(x2, 32); x3 |= __shfl_xor(x3, 32);                       \
    A0 |= x0; A1 |= x1; A2 |= x2; A3 |= x3;                                   \
  }

#define NMS_STEP(CS, PB, AW)                                                  \
  {                                                                           \
    const int c_ = g * 8 + (CS);                                              \
    if (v == g) {                                                             \
      unsigned acur = __builtin_amdgcn_readlane((AW), ((CS) >> 2));           \
      unsigned lo_ = (unsigned)c_ * 32u;                                      \
      unsigned init_ = (count >= lo_ + 32u) ? 0xFFFFFFFFu                     \
                     : (count <= lo_ ? 0u : ((1u << (count - lo_)) - 1u));    \
      unsigned w_ = init_ & ~acur;                                            \
      _Pragma("unroll") for (int k = 0; k < 32; k++) {                        \
        unsigned d_ = __builtin_amdgcn_readlane(dg[k], c_);                   \
        w_ &= ~(((w_ >> k) & 1u) ? d_ : 0u);                                  \
      }                                                                       \
      if (l == 0) {                                                           \
        keepw[c_] = w_;                                                       \
        __hip_atomic_store(&flagw[c_], 1u, __ATOMIC_RELEASE,                  \
                           __HIP_MEMORY_SCOPE_WORKGROUP);                     \
      }                                                                       \
      NMS_APPLY(w_, PB)                                                       \
      if (c_ + 8 < 64) PB = bp[(size_t)(c_ + 8) * 512];                       \
    } else if (v > g) {                                                       \
      while (__hip_atomic_load(&flagw[c_], __ATOMIC_ACQUIRE,                  \
                               __HIP_MEMORY_SCOPE_WORKGROUP) == 0u)           \
        __builtin_amdgcn_s_sleep(1);                                          \
      unsigned w_ = __builtin_amdgcn_readfirstlane(keepw[c_]);                \
      NMS_APPLY(w_, PB)                                                       \
      if (c_ + 8 < 64) PB = bp[(size_t)(c_ + 8) * 512];                       \
    }                                                                         \
  }

#pragma unroll 1
  for (int g = 0; g < 8; g++) {
    NMS_STEP(0, P0, A0)
    NMS_STEP(1, P1, A1)
    NMS_STEP(2, P2, A2)
    NMS_STEP(3, P3, A3)
    NMS_STEP(4, P4, A0)
    NMS_STEP(5, P5, A1)
    NMS_STEP(6, P6, A2)
    NMS_STEP(7, P7, A3)
  }
#undef NMS_STEP
#undef NMS_APPLY

  __syncthreads();
  float ds = dsp[0];
  for (int rr = tid; rr < TOPK; rr += 512) {
    bool kept = (keepw[rr >> 5] >> (rr & 31)) & 1u;
    float o[15];
    if (kept) {
      unsigned a = tidx[rr];
      float cx, cy, s; const float* bb; const float* lm;
      decode(a, b8, l8, b16, l16, b32, l32, cx, cy, s, bb, lm);
      o[0] = tconf[rr];
      float b0 = bb[0] * s, b1 = bb[1] * s, b2 = bb[2] * s, b3 = bb[3] * s;
      o[1] = (cx - b0) / ds;
      o[2] = (cy - b1) / ds;
      o[3] = (cx + b2) / ds;
      o[4] = (cy + b3) / ds;
      for (int p = 0; p < 5; p++) {
        float lx = lm[2 * p] * s, ly = lm[2 * p + 1] * s;
        o[5 + 2 * p] = (cx + lx) / ds;
        o[6 + 2 * p] = (cy + ly) / ds;
      }
    } else {
      for (int cc = 0; cc < 15; cc++) o[cc] = 0.f;
    }
    for (int cc = 0; cc < 15; cc++) out[(size_t)rr * 15 + cc] = o[cc];
  }
}

extern "C" void kernel_launch(void* const* d_in, const int* in_sizes, int n_in,
                              void* d_out, int out_size, void* d_ws, size_t ws_size,
                              hipStream_t stream) {
  const float* s8  = (const float*)d_in[0];
  const float* b8  = (const float*)d_in[1];
  const float* l8  = (const float*)d_in[2];
  const float* s16 = (const float*)d_in[3];
  const float* b16 = (const float*)d_in[4];
  const float* l16 = (const float*)d_in[5];
  const float* s32 = (const float*)d_in[6];
  const float* b32 = (const float*)d_in[7];
  const float* l32 = (const float*)d_in[8];
  const float* dsp = (const float*)d_in[9];
  char* ws = (char*)d_ws;
  unsigned* hist = (unsigned*)(ws + OFF_HIST);
  unsigned* meta = (unsigned*)(ws + OFF_META);
  unsigned long long* cand = (unsigned long long*)(ws + OFF_CAND);
  unsigned* tidx = (unsigned*)(ws + OFF_TIDX);
  float* tconf = (float*)(ws + OFF_TCONF);
  float* box = (float*)(ws + OFF_BOX);
  unsigned* diagT = (unsigned*)(ws + OFF_DIAGT);
  unsigned* supp_t = (unsigned*)(ws + OFF_SUPPT);
  float* out = (float*)d_out;

  hipMemsetAsync(ws, 0, OFF_META + 64, stream);  // hist + meta
  k_hist<<<2048, 256, 0, stream>>>(s8, s16, s32, hist);
  k_scan<<<1, 1024, 0, stream>>>(hist, meta);
  k_compact<<<2048, 256, 0, stream>>>(s8, s16, s32, meta, cand);
  k_rank<<<CAND_MAX / 4, 256, 0, stream>>>(cand, meta, b8, l8, b16, l16, b32, l32,
                                           dsp, tidx, tconf, box);
  k_supp<<<TOPK, 256, 0, stream>>>(box, (unsigned long long*)supp_t, diagT);
  k_nms_out<<<1, 512, 0, stream>>>(supp_t, diagT, meta, tidx, tconf,
                                   b8, l8, b16, l16, b32, l32, dsp, out);
}

// Round 15
// 132.367 us; speedup vs baseline: 1.1593x; 1.1593x over previous
//
#include <hip/hip_runtime.h>
#include <stdint.h>
#include <stddef.h>

// Match numpy float32 rounding: forbid fma contraction in all float math below.
#pragma clang fp contract(off)

#define N8   819200u
#define N16  204800u
#define N32  51200u
#define NTOT 1075200u
#define TOPK 2048
#define CAND_MAX 8192
#define NBIN 8192u
#define BINSHIFT 10
#define NMS_THR 0.4f
#define DET_THR 0.5f
#define LCAP 2048u   // per-chunk sparse-entry capacity (= exact worst case 32x64)

// ws byte offsets
#define OFF_HIST   0u        // u32[8192]    32KB
#define OFF_META   32768u    // u32[16]
#define OFF_CNT    32832u    // u32[64]      per-chunk entry counts
#define OFF_CAND   33088u    // u64[8192]    64KB
#define OFF_TIDX   98624u    // u32[2048]
#define OFF_TCONF  106816u   // f32[2048]
#define OFF_BOX    115008u   // f32[2048*4]  (16B aligned)
#define OFF_DIAGT  147776u   // u32[32][64]  8KB, [rowk][chunk]
#define OFF_LIST   155968u   // u64[64][2048] = 1MB sparse entries

__device__ __forceinline__ float load_conf(unsigned a, const float* __restrict__ s8,
                                           const float* __restrict__ s16,
                                           const float* __restrict__ s32) {
  if (a < N8) return s8[a];
  if (a < N8 + N16) return s16[a - N8];
  return s32[a - (N8 + N16)];
}

__device__ __forceinline__ void decode(unsigned a,
    const float* __restrict__ b8, const float* __restrict__ l8,
    const float* __restrict__ b16, const float* __restrict__ l16,
    const float* __restrict__ b32, const float* __restrict__ l32,
    float& cx, float& cy, float& s, const float*& bb, const float*& lm) {
  if (a < N8) {
    unsigned cell = a >> 1;
    cx = (float)((cell % 640u) * 8u); cy = (float)((cell / 640u) * 8u);
    s = 8.f; bb = b8 + (size_t)a * 4; lm = l8 + (size_t)a * 10;
  } else if (a < N8 + N16) {
    unsigned loc = a - N8; unsigned cell = loc >> 1;
    cx = (float)((cell % 320u) * 16u); cy = (float)((cell / 320u) * 16u);
    s = 16.f; bb = b16 + (size_t)loc * 4; lm = l16 + (size_t)loc * 10;
  } else {
    unsigned loc = a - (N8 + N16); unsigned cell = loc >> 1;
    cx = (float)((cell % 160u) * 32u); cy = (float)((cell / 160u) * 32u);
    s = 32.f; bb = b32 + (size_t)loc * 4; lm = l32 + (size_t)loc * 10;
  }
}

// K1: histogram of conf>=0.5 on 13-bit prefix of (bits - bits(0.5))
__global__ void k_hist(const float* __restrict__ s8, const float* __restrict__ s16,
                       const float* __restrict__ s32, unsigned* __restrict__ hist) {
  unsigned i = blockIdx.x * blockDim.x + threadIdx.x;
  unsigned st = gridDim.x * blockDim.x;
  for (unsigned a = i; a < NTOT; a += st) {
    float c = load_conf(a, s8, s16, s32);
    if (c >= DET_THR) {
      unsigned v = (__float_as_uint(c) - 0x3F000000u) >> BINSHIFT;
      if (v > NBIN - 1u) v = NBIN - 1u;
      atomicAdd(&hist[v], 1u);
    }
  }
}

// K2: find cutoff prefix (smallest p with suffix-count >= TOPK); single WG
__global__ void __launch_bounds__(1024) k_scan(const unsigned* __restrict__ hist,
                                               unsigned* __restrict__ meta) {
  __shared__ unsigned suf[1024];
  int t = threadIdx.x;
  const unsigned* hp = hist + (size_t)t * 8;
  unsigned s = 0;
  for (int b = 0; b < 8; b++) s += hp[b];
  suf[t] = s;
  __syncthreads();
  for (int d = 1; d < 1024; d <<= 1) {
    unsigned v = (t + d < 1024) ? suf[t + d] : 0u;
    __syncthreads();
    suf[t] += v;
    __syncthreads();
  }
  unsigned total = suf[0];
  unsigned mine = suf[t];
  unsigned nxt = (t < 1023) ? suf[t + 1] : 0u;
  if (total < (unsigned)TOPK) {
    if (t == 0) { meta[0] = 0u; meta[2] = total; }
    return;
  }
  if (mine >= (unsigned)TOPK && nxt < (unsigned)TOPK) {
    unsigned run = nxt, cut = (unsigned)t * 8u;
    for (int b = 7; b >= 0; b--) {
      run += hp[b];
      if (run >= (unsigned)TOPK) { cut = (unsigned)t * 8u + (unsigned)b; break; }
    }
    meta[0] = cut; meta[2] = total;
  }
}

// K3: compact candidates (>= cutoff prefix) as 64-bit sort keys
__global__ void k_compact(const float* __restrict__ s8, const float* __restrict__ s16,
                          const float* __restrict__ s32, unsigned* __restrict__ meta,
                          unsigned long long* __restrict__ cand) {
  unsigned cut = meta[0];
  unsigned i = blockIdx.x * blockDim.x + threadIdx.x;
  unsigned st = gridDim.x * blockDim.x;
  for (unsigned a = i; a < NTOT; a += st) {
    float c = load_conf(a, s8, s16, s32);
    if (c >= DET_THR) {
      unsigned b = __float_as_uint(c);
      unsigned v = (b - 0x3F000000u) >> BINSHIFT;
      if (v >= cut) {
        unsigned pos = atomicAdd(&meta[3], 1u);
        if (pos < (unsigned)CAND_MAX)
          cand[pos] = ((unsigned long long)b << 32) |
                      (unsigned long long)(0xFFFFFFFFu - a);
      }
    }
  }
}

// K4: rank-and-scatter. Keys unique -> rank(x)=#{y>x} is a permutation.
__global__ void __launch_bounds__(256) k_rank(
    const unsigned long long* __restrict__ cand, const unsigned* __restrict__ meta,
    const float* __restrict__ b8, const float* __restrict__ l8,
    const float* __restrict__ b16, const float* __restrict__ l16,
    const float* __restrict__ b32, const float* __restrict__ l32,
    const float* __restrict__ dsp,
    unsigned* __restrict__ tidx, float* __restrict__ tconf, float* __restrict__ box) {
  unsigned count = meta[3];
  if (count > (unsigned)CAND_MAX) count = (unsigned)CAND_MAX;
  unsigned wave = blockIdx.x * 4u + (threadIdx.x >> 6);
  unsigned lane = threadIdx.x & 63u;
  if (wave >= count) return;
  unsigned long long my = cand[wave];
  unsigned cnt = 0;
  for (unsigned i = lane; i < count; i += 64u)
    cnt += (cand[i] > my) ? 1u : 0u;
  for (int d = 32; d > 0; d >>= 1) cnt += __shfl_down(cnt, d);
  if (lane == 0 && cnt < (unsigned)TOPK) {
    unsigned r = cnt;
    unsigned a = 0xFFFFFFFFu - (unsigned)(my & 0xFFFFFFFFull);
    float conf = __uint_as_float((unsigned)(my >> 32));
    float cx, cy, s; const float* bb; const float* lm;
    decode(a, b8, l8, b16, l16, b32, l32, cx, cy, s, bb, lm);
    float ds = dsp[0];
    float b0 = bb[0] * s, b1 = bb[1] * s, b2 = bb[2] * s, b3 = bb[3] * s;
    box[r * 4 + 0] = (cx - b0) / ds;
    box[r * 4 + 1] = (cy - b1) / ds;
    box[r * 4 + 2] = (cx + b2) / ds;
    box[r * 4 + 3] = (cy + b3) / ds;
    tidx[r] = a; tconf[r] = conf;
  }
}

// K5: SPARSE suppression. For row i (chunk c=i>>5, k=i&31): diagT[k][c] =
// within-chunk u32 word (j in [32c,32c+32)); every OTHER nonzero u32 word w
// is appended to chunk c's entry list as (bits<<32)|(k<<6)|w. pred includes
// j>i so w >= c always; w==c excluded (closure handles it via diag).
__global__ void __launch_bounds__(256) k_supp(const float* __restrict__ box,
                                              unsigned long long* __restrict__ listg,
                                              unsigned* __restrict__ cntg,
                                              unsigned* __restrict__ diagT) {
  int i = blockIdx.x;
  const float4 bi = ((const float4*)box)[i];
  float ai = fmaxf(bi.z - bi.x, 0.f) * fmaxf(bi.w - bi.y, 0.f);
  int tid = threadIdx.x;
  int lane = tid & 63, wv = tid >> 6;
  int c = i >> 5, k = i & 31;
  for (int base = 0; base < TOPK; base += 256) {
    int j = base + tid;
    const float4 bj = ((const float4*)box)[j];
    float aj = fmaxf(bj.z - bj.x, 0.f) * fmaxf(bj.w - bj.y, 0.f);
    float ltx = fmaxf(bi.x, bj.x), lty = fmaxf(bi.y, bj.y);
    float rbx = fminf(bi.z, bj.z), rby = fminf(bi.w, bj.w);
    float w = fmaxf(rbx - ltx, 0.f), h = fmaxf(rby - lty, 0.f);
    float inter = w * h;
    float iou = inter / (ai + aj - inter + 1e-9f);
    bool pred = (iou > NMS_THR) && (j > i);
    unsigned long long word = __ballot(pred);
    int w64 = (base >> 6) + wv;
    if (lane == 0) {
      if (w64 == (i >> 6))
        __builtin_nontemporal_store(
            (unsigned)(word >> (((i >> 5) & 1) * 32)), &diagT[k * 64 + c]);
      unsigned lo32 = (unsigned)word;
      unsigned hi32 = (unsigned)(word >> 32);
      int w0 = 2 * w64, w1 = 2 * w64 + 1;
      if (lo32 != 0u && w0 != c) {
        unsigned pos = atomicAdd(&cntg[c], 1u);
        if (pos < LCAP)
          listg[(size_t)c * LCAP + pos] =
              ((unsigned long long)lo32 << 32) | (unsigned)((k << 6) | w0);
      }
      if (hi32 != 0u && w1 != c) {
        unsigned pos = atomicAdd(&cntg[c], 1u);
        if (pos < LCAP)
          listg[(size_t)c * LCAP + pos] =
              ((unsigned long long)hi32 << 32) | (unsigned)((k << 6) | w1);
      }
    }
  }
}

// K6: sparse greedy NMS (single wave) + output (256 threads).
// acc[64] in LDS = OR of kept rows' suppression words (columns). Per chunk:
// ds_read acc[ch] (uniform) -> readfirstlane -> readlane+SALU closure over
// preloaded diag VGPRs -> publish keepw[ch] -> apply sparse entries via
// gated ds_atomicOr (lane e handles entry e; entries prefetched 4 chunks
// ahead, 8B/lane). LDS ops are wave-in-order, so next chunk's acc read sees
// this chunk's atomics. ~500cy/chunk critical path; global traffic ~20KB.
__global__ void __launch_bounds__(256, 1) k_nms_out(
    const unsigned long long* __restrict__ listg, const unsigned* __restrict__ cntg,
    const unsigned* __restrict__ diagT, const unsigned* __restrict__ meta,
    const unsigned* __restrict__ tidx, const float* __restrict__ tconf,
    const float* __restrict__ b8, const float* __restrict__ l8,
    const float* __restrict__ b16, const float* __restrict__ l16,
    const float* __restrict__ b32, const float* __restrict__ l32,
    const float* __restrict__ dsp, float* __restrict__ out) {
  __shared__ unsigned keepw[64];
  __shared__ unsigned acc[64];
  int tid = threadIdx.x;
  if (tid < 64) {
    const int l = tid;
    unsigned count = meta[3];
    if (count > (unsigned)TOPK) count = (unsigned)TOPK;
    acc[l] = 0u;
    unsigned dg[32];
#pragma unroll
    for (int k = 0; k < 32; k++) dg[k] = diagT[k * 64 + l];
    unsigned cntv = cntg[l];
    if (cntv > LCAP) cntv = LCAP;
    unsigned long long p0 = listg[(size_t)0 * LCAP + l];
    unsigned long long p1 = listg[(size_t)1 * LCAP + l];
    unsigned long long p2 = listg[(size_t)2 * LCAP + l];
    unsigned long long p3 = listg[(size_t)3 * LCAP + l];

#define NSTEP(PB, CC)                                                         \
  {                                                                           \
    const int ch = (CC);                                                      \
    unsigned cnt_c = __builtin_amdgcn_readlane(cntv, ch);                     \
    unsigned av = acc[ch];                                                    \
    unsigned a0 = __builtin_amdgcn_readfirstlane(av);                         \
    unsigned lo_ = (unsigned)ch * 32u;                                        \
    unsigned init_ = (count >= lo_ + 32u) ? 0xFFFFFFFFu                       \
                   : (count <= lo_ ? 0u : ((1u << (count - lo_)) - 1u));      \
    unsigned w_ = init_ & ~a0;                                                \
    _Pragma("unroll") for (int k = 0; k < 32; k++) {                          \
      unsigned d_ = __builtin_amdgcn_readlane(dg[k], ch);                     \
      w_ &= ~(((w_ >> k) & 1u) ? d_ : 0u);                                    \
    }                                                                         \
    if (l == 0) keepw[ch] = w_;                                               \
    if (cnt_c != 0u) {                                                        \
      unsigned elo = (unsigned)PB;                                            \
      unsigned ebits = (unsigned)(PB >> 32);                                  \
      unsigned we = elo & 63u, ke = (elo >> 6) & 31u;                         \
      if (((unsigned)l < cnt_c) && ((w_ >> ke) & 1u))                         \
        atomicOr(&acc[we], ebits);                                            \
      for (unsigned base = 64u; base < cnt_c; base += 64u) {                  \
        unsigned idx = base + (unsigned)l;                                    \
        if (idx < cnt_c) {                                                    \
          unsigned long long e2 = listg[(size_t)ch * LCAP + idx];             \
          unsigned lo2 = (unsigned)e2;                                        \
          if ((w_ >> ((lo2 >> 6) & 31u)) & 1u)                                \
            atomicOr(&acc[lo2 & 63u], (unsigned)(e2 >> 32));                  \
        }                                                                     \
      }                                                                       \
    }                                                                         \
    if (ch + 4 < 64) PB = listg[(size_t)(ch + 4) * LCAP + l];                 \
  }

#pragma unroll 1
    for (int c = 0; c < 64; c += 4) {
      NSTEP(p0, c + 0)
      NSTEP(p1, c + 1)
      NSTEP(p2, c + 2)
      NSTEP(p3, c + 3)
    }
#undef NSTEP
  }
  __syncthreads();
  float ds = dsp[0];
  for (int rr = tid; rr < TOPK; rr += 256) {
    bool kept = (keepw[rr >> 5] >> (rr & 31)) & 1u;
    float o[15];
    if (kept) {
      unsigned a = tidx[rr];
      float cx, cy, s; const float* bb; const float* lm;
      decode(a, b8, l8, b16, l16, b32, l32, cx, cy, s, bb, lm);
      o[0] = tconf[rr];
      float b0 = bb[0] * s, b1 = bb[1] * s, b2 = bb[2] * s, b3 = bb[3] * s;
      o[1] = (cx - b0) / ds;
      o[2] = (cy - b1) / ds;
      o[3] = (cx + b2) / ds;
      o[4] = (cy + b3) / ds;
      for (int p = 0; p < 5; p++) {
        float lx = lm[2 * p] * s, ly = lm[2 * p + 1] * s;
        o[5 + 2 * p] = (cx + lx) / ds;
        o[6 + 2 * p] = (cy + ly) / ds;
      }
    } else {
      for (int cc = 0; cc < 15; cc++) o[cc] = 0.f;
    }
    for (int cc = 0; cc < 15; cc++) out[(size_t)rr * 15 + cc] = o[cc];
  }
}

extern "C" void kernel_launch(void* const* d_in, const int* in_sizes, int n_in,
                              void* d_out, int out_size, void* d_ws, size_t ws_size,
                              hipStream_t stream) {
  const float* s8  = (const float*)d_in[0];
  const float* b8  = (const float*)d_in[1];
  const float* l8  = (const float*)d_in[2];
  const float* s16 = (const float*)d_in[3];
  const float* b16 = (const float*)d_in[4];
  const float* l16 = (const float*)d_in[5];
  const float* s32 = (const float*)d_in[6];
  const float* b32 = (const float*)d_in[7];
  const float* l32 = (const float*)d_in[8];
  const float* dsp = (const float*)d_in[9];
  char* ws = (char*)d_ws;
  unsigned* hist = (unsigned*)(ws + OFF_HIST);
  unsigned* meta = (unsigned*)(ws + OFF_META);
  unsigned* cnt = (unsigned*)(ws + OFF_CNT);
  unsigned long long* cand = (unsigned long long*)(ws + OFF_CAND);
  unsigned* tidx = (unsigned*)(ws + OFF_TIDX);
  float* tconf = (float*)(ws + OFF_TCONF);
  float* box = (float*)(ws + OFF_BOX);
  unsigned* diagT = (unsigned*)(ws + OFF_DIAGT);
  unsigned long long* listg = (unsigned long long*)(ws + OFF_LIST);
  float* out = (float*)d_out;

  hipMemsetAsync(ws, 0, OFF_CAND, stream);  // hist + meta + cnt
  k_hist<<<2048, 256, 0, stream>>>(s8, s16, s32, hist);
  k_scan<<<1, 1024, 0, stream>>>(hist, meta);
  k_compact<<<2048, 256, 0, stream>>>(s8, s16, s32, meta, cand);
  k_rank<<<CAND_MAX / 4, 256, 0, stream>>>(cand, meta, b8, l8, b16, l16, b32, l32,
                                           dsp, tidx, tconf, box);
  k_supp<<<TOPK, 256, 0, stream>>>(box, listg, cnt, diagT);
  k_nms_out<<<1, 256, 0, stream>>>(listg, cnt, diagT, meta, tidx, tconf,
                                   b8, l8, b16, l16, b32, l32, dsp, out);
}